// Round 1
// 421.516 us; speedup vs baseline: 1.8575x; 1.8575x over previous
//
#include <hip/hip_runtime.h>
#include <hip/hip_bf16.h>

#define BB 8
#define CC 512
#define HO 64
#define HP 66
#define NPIX (BB*HO*HO)   // 32768

typedef float f32x4 __attribute__((ext_vector_type(4)));
typedef __bf16 bf16x8 __attribute__((ext_vector_type(8)));
using bf16 = __hip_bfloat16;

__device__ __forceinline__ void gload16(const void* g, void* l) {
    __builtin_amdgcn_global_load_lds((const __attribute__((address_space(1))) void*)g,
                                     (__attribute__((address_space(3))) void*)l, 16, 0, 0);
}

__device__ __forceinline__ float waveRedSum(float v) {
    #pragma unroll
    for (int off = 32; off; off >>= 1) v += __shfl_down(v, off);
    return v;
}

// thread t -> (i = t&511, o = t>>9). Reads W[i][o][0..8] (contiguous 36B),
// writes S2ho[o][i] = he^2 * sum W^2, and keffT[tap][o][i] = he*W[i][o][8-tap].
__global__ void prep_weights(const float* __restrict__ Wsrc, float* __restrict__ S2ho,
                             bf16* __restrict__ keffT, float he) {
    int t = blockIdx.x * blockDim.x + threadIdx.x;
    int i = t & (CC-1), o = t >> 9;
    const float* wp = Wsrc + (i*CC + o)*9;
    float v[9]; float s2 = 0.f;
    #pragma unroll
    for (int k = 0; k < 9; ++k) { v[k] = wp[k] * he; s2 += v[k]*v[k]; }
    S2ho[o*CC + i] = s2;
    #pragma unroll
    for (int tp = 0; tp < 9; ++tp) keffT[(tp*CC + o)*CC + i] = (bf16)v[8 - tp];
}

// one wave per (set, b, i): style[b,i] = sum_d w[b,d]*A[i,d]/sqrt(512) + Ab[i]
__global__ void style_kernel(const float* __restrict__ w,
                             const float* __restrict__ A1, const float* __restrict__ A1b,
                             const float* __restrict__ A2, const float* __restrict__ A2b,
                             float* __restrict__ s1, float* __restrict__ s2) {
    int wid = (blockIdx.x * blockDim.x + threadIdx.x) >> 6;
    int lane = threadIdx.x & 63;
    int set = wid >= BB*CC; int rem = set ? wid - BB*CC : wid;
    int b = rem >> 9, i = rem & (CC-1);
    const float* A = set ? A2 : A1;
    const float* wb = w + b*CC;
    float sum = 0.f;
    for (int d = lane; d < CC; d += 64) sum += wb[d] * A[i*CC + d];
    sum = waveRedSum(sum);
    if (lane == 0) {
        float r = sum * 0.04419417382415922f + (set ? A2b : A1b)[i];
        (set ? s2 : s1)[b*CC + i] = r;
    }
}

// one wave per (set, b, o): dg = gain * rsqrt(sum_i style^2 * S2ho[o][i] + eps)
__global__ void demod_kernel(const float* __restrict__ s1, const float* __restrict__ S21,
                             const float* __restrict__ s2, const float* __restrict__ S22,
                             float* __restrict__ dg1, float* __restrict__ dg2, float gain) {
    int wid = (blockIdx.x * blockDim.x + threadIdx.x) >> 6;
    int lane = threadIdx.x & 63;
    int set = wid >= BB*CC; int rem = set ? wid - BB*CC : wid;
    int b = rem >> 9, o = rem & (CC-1);
    const float* st = (set ? s2 : s1) + b*CC;
    const float* S2 = (set ? S22 : S21) + o*CC;
    float sum = 0.f;
    for (int i = lane; i < CC; i += 64) { float sv = st[i]; sum += sv*sv*S2[i]; }
    sum = waveRedSum(sum);
    if (lane == 0) (set ? dg2 : dg1)[b*CC + o] = gain * rsqrtf(sum + 1e-8f);
}

// block = (b, p, q-group of 4), 512 threads = channels.
// Each thread loads 2 rows x 8 floats (4x f32x4) from its input plane, bounces
// them through LDS (transposed [slot][ch] -> conflict-free, enables dynamic
// corner indexing without scratch), computes 4 output pixels.
__global__ void upsample_mod(const float* __restrict__ x, const float* __restrict__ s1,
                             bf16* __restrict__ xs1) {
    __shared__ float usl[16][CC];
    int blk = blockIdx.x;
    int i = threadIdx.x;
    int b = blk >> 10, rem = blk & 1023, p = rem >> 4, q0 = (rem & 15) << 2;
    const float scale = 31.0f / 63.0f;
    float chf = p * scale; int h0 = (int)chf; float fh = chf - h0; int h1 = min(h0 + 1, 31);
    int wa = min(((int)(q0 * scale)) & ~3, 24);    // 4-aligned, wa+7 <= 31
    const float* xb = x + ((size_t)(b*CC + i) << 10);
    f32x4 r00 = *(const f32x4*)(xb + (h0 << 5) + wa);
    f32x4 r01 = *(const f32x4*)(xb + (h0 << 5) + wa + 4);
    f32x4 r10 = *(const f32x4*)(xb + (h1 << 5) + wa);
    f32x4 r11 = *(const f32x4*)(xb + (h1 << 5) + wa + 4);
    #pragma unroll
    for (int k = 0; k < 4; ++k) {
        usl[k][i] = r00[k]; usl[4 + k][i] = r01[k];
        usl[8 + k][i] = r10[k]; usl[12 + k][i] = r11[k];
    }
    float sv = s1[b*CC + i];
    // no barrier needed: each thread reads only its own column
    #pragma unroll
    for (int dq = 0; dq < 4; ++dq) {
        int q = q0 + dq;
        float cwf = q * scale; int w0 = (int)cwf; float fw = cwf - w0;
        int i0 = w0 - wa, i1 = min(w0 + 1, 31) - wa;
        float v00 = usl[i0][i], v01 = usl[i1][i];
        float v10 = usl[8 + i0][i], v11 = usl[8 + i1][i];
        float va = v00*(1.f-fh) + v10*fh;
        float vb = v01*(1.f-fh) + v11*fh;
        float v  = (va*(1.f-fw) + vb*fw) * sv;
        xs1[(((b*HP) + p + 1)*HP + (q + 1))*CC + i] = (bf16)v;
    }
}

// Implicit-GEMM 3x3 conv. M=32768 pixels, N=512, K=512 per tap * 9 taps.
// 128x128 tile, BK=64, 4 waves (2x2), each 64x64 via 4x4 of mfma_f32_16x16x32_bf16.
// LDS rows are 128B (32 banks) with slot ^= row&7 XOR swizzle -> conflict-free
// ds_read_b128. Double-buffered prefetch: stage step s+1 before computing step s,
// one __syncthreads (vmcnt0 drain) per K-step -> loads fly under the 32 MFMAs.
template<int PHASE>
__global__ __launch_bounds__(256, 2) void conv_gemm(
    const bf16* __restrict__ xs, const bf16* __restrict__ keffT,
    const float* __restrict__ dg, const float* __restrict__ noise,
    const float* __restrict__ nsw, const float* __restrict__ nsb,
    const float* __restrict__ nbw, const float* __restrict__ nbb,
    const float* __restrict__ biasv, const float* __restrict__ stnext,
    bf16* __restrict__ outb, float* __restrict__ outf) {
    __shared__ __attribute__((aligned(16))) bf16 As0[8192];
    __shared__ __attribute__((aligned(16))) bf16 As1[8192];
    __shared__ __attribute__((aligned(16))) bf16 Bs0[8192];
    __shared__ __attribute__((aligned(16))) bf16 Bs1[8192];
    const int tid = threadIdx.x;
    const int wave = tid >> 6, lane = tid & 63;

    // XCD-chunked tile swizzle (1024 wgs, %8==0 -> bijective): the 4 ntiles
    // sharing an A-panel land on the same XCD's L2.
    const int tileId = ((blockIdx.x & 7) << 7) + (blockIdx.x >> 3);
    const int mtile = tileId >> 2, ntile = tileId & 3;
    const int m0 = mtile << 7, n0 = ntile << 7;
    const int b  = m0 >> 12;
    const int p0 = (m0 & 4095) >> 6;
    const int wm = wave >> 1, wn = wave & 1;

    // ---- staging geometry: per round j (0..3), wave w covers rows w*8+j*32..+7
    const int lr = lane >> 3;                       // row within 8-group (== row&7)
    const int srcSwz = (((lane & 7) ^ lr) << 4);    // pre-swizzled source slot
    const int w8lr = (wave << 3) + lr;              // 0..31
    int rowOffA[4], rowOffB[4];
    #pragma unroll
    for (int j = 0; j < 4; ++j) {
        int q = ((j & 1) << 5) + w8lr;              // 0..63
        rowOffA[j] = ((j >> 1)*HP + q)*(CC*2) + srcSwz;
        rowOffB[j] = ((j << 5) + w8lr)*(CC*2) + srcSwz;
    }
    char* const dA0 = (char*)As0 + tid*16;
    char* const dA1 = (char*)As1 + tid*16;
    char* const dB0 = (char*)Bs0 + tid*16;
    char* const dB1 = (char*)Bs1 + tid*16;

    // ---- fragment read offsets (row*128 + (slot ^ (row&7))*16)
    const int l15 = lane & 15;
    const int aBase = ((wm << 6) + l15) << 7;
    const int bBase = ((wn << 6) + l15) << 7;
    int swzK[2];
    #pragma unroll
    for (int kc = 0; kc < 2; ++kc)
        swzK[kc] = ((((lane >> 4) | (kc << 2)) ^ (lane & 7)) << 4);

    f32x4 acc[4][4];
    #pragma unroll
    for (int i_ = 0; i_ < 4; ++i_)
        #pragma unroll
        for (int j_ = 0; j_ < 4; ++j_) acc[i_][j_] = f32x4{0.f, 0.f, 0.f, 0.f};

    // step s (0..71): tap t = s>>3, k0 bytes = (s&7)<<7
    auto stage = [&](int s, char* lA, char* lB) {
        const int t = s >> 3;
        const int k0b = (s & 7) << 7;
        const int dh = (t * 11) >> 5;               // t/3 for t in 0..8
        const int dwq = t - dh*3;
        const char* bA = (const char*)xs + (((b*HP + p0 + dh)*HP + dwq)*CC)*2 + k0b;
        const char* bB = (const char*)keffT + ((t*CC + n0)*CC)*2 + k0b;
        #pragma unroll
        for (int j = 0; j < 4; ++j) {
            gload16(bA + rowOffA[j], lA + j*4096);
            gload16(bB + rowOffB[j], lB + j*4096);
        }
    };

    auto compute = [&](const bf16* Abuf, const bf16* Bbuf) {
        const char* sA = (const char*)Abuf;
        const char* sB = (const char*)Bbuf;
        bf16x8 af[4][2], bv[4][2];
        #pragma unroll
        for (int f = 0; f < 4; ++f)
            #pragma unroll
            for (int kc = 0; kc < 2; ++kc) {
                af[f][kc] = *(const bf16x8*)(sA + aBase + f*2048 + swzK[kc]);
                bv[f][kc] = *(const bf16x8*)(sB + bBase + f*2048 + swzK[kc]);
            }
        #pragma unroll
        for (int kc = 0; kc < 2; ++kc)
            #pragma unroll
            for (int fm = 0; fm < 4; ++fm)
                #pragma unroll
                for (int fn = 0; fn < 4; ++fn)
                    acc[fm][fn] = __builtin_amdgcn_mfma_f32_16x16x32_bf16(
                        af[fm][kc], bv[fn][kc], acc[fm][fn], 0, 0, 0);
    };

    stage(0, dA0, dB0);
    __syncthreads();
    #pragma unroll 1
    for (int it = 0; it < 36; ++it) {
        const int s0 = it << 1;
        stage(s0 + 1, dA1, dB1);
        compute(As0, Bs0);
        __syncthreads();
        if (it < 35) stage(s0 + 2, dA0, dB0);
        compute(As1, Bs1);
        __syncthreads();
    }

    // epilogue: v*dg -> noise modulation -> +bias -> lrelu -> route
    const float* dgb = dg + b*CC;
    int nIdx[4]; float pdg[4], pnsw[4], pnsb[4], pnbw[4], pnbb[4], pbias[4], pst[4];
    #pragma unroll
    for (int fn = 0; fn < 4; ++fn) {
        int n = n0 + (wn << 6) + (fn << 4) + (lane & 15);
        nIdx[fn] = n;
        pdg[fn] = dgb[n]; pnsw[fn] = nsw[n]; pnsb[fn] = nsb[n];
        pnbw[fn] = nbw[n]; pnbb[fn] = nbb[n]; pbias[fn] = biasv[n];
        if (PHASE == 1) pst[fn] = stnext[b*CC + n]; else pst[fn] = 0.f;
    }
    #pragma unroll
    for (int fm = 0; fm < 4; ++fm) {
        #pragma unroll
        for (int r = 0; r < 4; ++r) {
            int mloc = m0 + (wm << 6) + (fm << 4) + ((lane >> 4) << 2) + r;
            float ns = noise[mloc];
            int prow = (mloc & 4095) >> 6, qcol = mloc & 63;
            #pragma unroll
            for (int fn = 0; fn < 4; ++fn) {
                float v = acc[fm][fn][r] * pdg[fn];
                v = v * (ns*pnsw[fn] + pnsb[fn]) + (ns*pnbw[fn] + pnbb[fn]) + pbias[fn];
                v = fmaxf(v, 0.2f*v);   // leaky relu 0.2
                if (PHASE == 1) {
                    outb[(((b*HP) + prow + 1)*HP + (qcol + 1))*CC + nIdx[fn]] =
                        (bf16)(v * pst[fn]);
                } else {
                    outf[((b*CC + nIdx[fn]) << 12) + (mloc & 4095)] = v;
                }
            }
        }
    }
}

// block = 64 consecutive pixels, 4 waves split the o-range (128 each).
// Reads are coalesced (64 lanes x 4B contiguous per o), LDS-reduce across waves.
__global__ void rgb_kernel(const float* __restrict__ xf, const float* __restrict__ rgbw,
                           const float* __restrict__ rgbb, float* __restrict__ out) {
    __shared__ float red[3][4][64];
    int tid = threadIdx.x;
    int wv = tid >> 6, ln = tid & 63;
    int pix = blockIdx.x * 64 + ln;
    int b = pix >> 12, rem = pix & 4095;
    const float* xb = xf + (((size_t)b*CC) << 12) + rem;
    float a0 = 0.f, a1 = 0.f, a2 = 0.f;
    int o0 = wv << 7;
    #pragma unroll 8
    for (int o = o0; o < o0 + 128; ++o) {
        float xv = xb[(size_t)o << 12];
        a0 += xv * rgbw[o]; a1 += xv * rgbw[CC+o]; a2 += xv * rgbw[2*CC+o];
    }
    red[0][wv][ln] = a0; red[1][wv][ln] = a1; red[2][wv][ln] = a2;
    __syncthreads();
    if (wv == 0) {
        const float he = 0.03f * 0.04419417382415922f;
        #pragma unroll
        for (int c = 0; c < 3; ++c) {
            float s = red[c][0][ln] + red[c][1][ln] + red[c][2][ln] + red[c][3][ln];
            out[(b*3+c)*4096 + rem] = s*he + rgbb[c];
        }
    }
}

extern "C" void kernel_launch(void* const* d_in, const int* in_sizes, int n_in,
                              void* d_out, int out_size, void* d_ws, size_t ws_size,
                              hipStream_t stream) {
    const float* x      = (const float*)d_in[0];
    const float* w      = (const float*)d_in[1];
    const float* noise1 = (const float*)d_in[2];
    const float* noise2 = (const float*)d_in[3];
    const float* conv1w = (const float*)d_in[4];
    const float* bias1  = (const float*)d_in[5];
    const float* conv2w = (const float*)d_in[6];
    const float* bias2  = (const float*)d_in[7];
    const float* A1w = (const float*)d_in[8];
    const float* A1b = (const float*)d_in[9];
    const float* A2w = (const float*)d_in[10];
    const float* A2b = (const float*)d_in[11];
    const float* B1sw = (const float*)d_in[12];
    const float* B1sb = (const float*)d_in[13];
    const float* B1bw = (const float*)d_in[14];
    const float* B1bb = (const float*)d_in[15];
    const float* B2sw = (const float*)d_in[16];
    const float* B2sb = (const float*)d_in[17];
    const float* B2bw = (const float*)d_in[18];
    const float* B2bb = (const float*)d_in[19];
    const float* rgbw = (const float*)d_in[20];
    const float* rgbb = (const float*)d_in[21];

    char* ws = (char*)d_ws;
    size_t off = 0;
    auto alloc = [&](size_t bytes) { char* p = ws + off; off += (bytes + 255) & ~(size_t)255; return p; };
    const size_t xsBytes = (size_t)BB*HP*HP*CC*2;
    bf16* xs1 = (bf16*)alloc(xsBytes);
    bf16* xs2 = (bf16*)alloc(xsBytes);
    bf16* kT1 = (bf16*)alloc((size_t)9*CC*CC*2);
    bf16* kT2 = (bf16*)alloc((size_t)9*CC*CC*2);
    float* S21 = (float*)alloc((size_t)CC*CC*4);
    float* S22 = (float*)alloc((size_t)CC*CC*4);
    float* s1  = (float*)alloc(BB*CC*4);
    float* s2  = (float*)alloc(BB*CC*4);
    float* dg1 = (float*)alloc(BB*CC*4);
    float* dg2 = (float*)alloc(BB*CC*4);

    float* outx   = (float*)d_out;
    float* outrgb = outx + (size_t)BB*CC*HO*HO;

    hipMemsetAsync(xs1, 0, xsBytes, stream);
    hipMemsetAsync(xs2, 0, xsBytes, stream);

    const float gain = 1.41421356237309515f;
    const float he = gain / sqrtf(512.f * 9.f);
    prep_weights<<<CC*CC/256, 256, 0, stream>>>(conv1w, S21, kT1, he);
    prep_weights<<<CC*CC/256, 256, 0, stream>>>(conv2w, S22, kT2, he);
    style_kernel<<<2*BB*CC/4, 256, 0, stream>>>(w, A1w, A1b, A2w, A2b, s1, s2);
    demod_kernel<<<2*BB*CC/4, 256, 0, stream>>>(s1, S21, s2, S22, dg1, dg2, gain);
    upsample_mod<<<BB*HO*16, CC, 0, stream>>>(x, s1, xs1);
    conv_gemm<1><<<(NPIX/128)*(CC/128), 256, 0, stream>>>(
        xs1, kT1, dg1, noise1, B1sw, B1sb, B1bw, B1bb, bias1, s2, xs2, nullptr);
    conv_gemm<2><<<(NPIX/128)*(CC/128), 256, 0, stream>>>(
        xs2, kT2, dg2, noise2, B2sw, B2sb, B2bw, B2bb, bias2, nullptr, nullptr, outx);
    rgb_kernel<<<NPIX/64, 256, 0, stream>>>(outx, rgbw, rgbb, outrgb);
}

// Round 2
// 392.982 us; speedup vs baseline: 1.9924x; 1.0726x over previous
//
#include <hip/hip_runtime.h>
#include <hip/hip_bf16.h>

#define BB 8
#define CC 512
#define HO 64
#define HP 66
#define NPIX (BB*HO*HO)   // 32768

typedef float f32x4 __attribute__((ext_vector_type(4)));
typedef __bf16 bf16x8 __attribute__((ext_vector_type(8)));
using bf16 = __hip_bfloat16;

__device__ __forceinline__ void gload16(const void* g, void* l) {
    __builtin_amdgcn_global_load_lds((const __attribute__((address_space(1))) void*)g,
                                     (__attribute__((address_space(3))) void*)l, 16, 0, 0);
}

__device__ __forceinline__ float waveRedSum(float v) {
    #pragma unroll
    for (int off = 32; off; off >>= 1) v += __shfl_down(v, off);
    return v;
}

// thread t -> (i = t&511, o = t>>9). Reads W[i][o][0..8] (contiguous 36B),
// writes S2ho[o][i] = he^2 * sum W^2, and keffT[tap][o][i] = he*W[i][o][8-tap].
__global__ void prep_weights(const float* __restrict__ Wsrc, float* __restrict__ S2ho,
                             bf16* __restrict__ keffT, float he) {
    int t = blockIdx.x * blockDim.x + threadIdx.x;
    int i = t & (CC-1), o = t >> 9;
    const float* wp = Wsrc + (i*CC + o)*9;
    float v[9]; float s2 = 0.f;
    #pragma unroll
    for (int k = 0; k < 9; ++k) { v[k] = wp[k] * he; s2 += v[k]*v[k]; }
    S2ho[o*CC + i] = s2;
    #pragma unroll
    for (int tp = 0; tp < 9; ++tp) keffT[(tp*CC + o)*CC + i] = (bf16)v[8 - tp];
}

// one wave per (set, b, i): style[b,i] = sum_d w[b,d]*A[i,d]/sqrt(512) + Ab[i]
__global__ void style_kernel(const float* __restrict__ w,
                             const float* __restrict__ A1, const float* __restrict__ A1b,
                             const float* __restrict__ A2, const float* __restrict__ A2b,
                             float* __restrict__ s1, float* __restrict__ s2) {
    int wid = (blockIdx.x * blockDim.x + threadIdx.x) >> 6;
    int lane = threadIdx.x & 63;
    int set = wid >= BB*CC; int rem = set ? wid - BB*CC : wid;
    int b = rem >> 9, i = rem & (CC-1);
    const float* A = set ? A2 : A1;
    const float* wb = w + b*CC;
    float sum = 0.f;
    for (int d = lane; d < CC; d += 64) sum += wb[d] * A[i*CC + d];
    sum = waveRedSum(sum);
    if (lane == 0) {
        float r = sum * 0.04419417382415922f + (set ? A2b : A1b)[i];
        (set ? s2 : s1)[b*CC + i] = r;
    }
}

// one wave per (set, b, o): dg = gain * rsqrt(sum_i style^2 * S2ho[o][i] + eps)
__global__ void demod_kernel(const float* __restrict__ s1, const float* __restrict__ S21,
                             const float* __restrict__ s2, const float* __restrict__ S22,
                             float* __restrict__ dg1, float* __restrict__ dg2, float gain) {
    int wid = (blockIdx.x * blockDim.x + threadIdx.x) >> 6;
    int lane = threadIdx.x & 63;
    int set = wid >= BB*CC; int rem = set ? wid - BB*CC : wid;
    int b = rem >> 9, o = rem & (CC-1);
    const float* st = (set ? s2 : s1) + b*CC;
    const float* S2 = (set ? S22 : S21) + o*CC;
    float sum = 0.f;
    for (int i = lane; i < CC; i += 64) { float sv = st[i]; sum += sv*sv*S2[i]; }
    sum = waveRedSum(sum);
    if (lane == 0) (set ? dg2 : dg1)[b*CC + o] = gain * rsqrtf(sum + 1e-8f);
}

// block = (b, p, q-group of 4), 512 threads = channels.
__global__ void upsample_mod(const float* __restrict__ x, const float* __restrict__ s1,
                             bf16* __restrict__ xs1) {
    __shared__ float usl[16][CC];
    int blk = blockIdx.x;
    int i = threadIdx.x;
    int b = blk >> 10, rem = blk & 1023, p = rem >> 4, q0 = (rem & 15) << 2;
    const float scale = 31.0f / 63.0f;
    float chf = p * scale; int h0 = (int)chf; float fh = chf - h0; int h1 = min(h0 + 1, 31);
    int wa = min(((int)(q0 * scale)) & ~3, 24);    // 4-aligned, wa+7 <= 31
    const float* xb = x + ((size_t)(b*CC + i) << 10);
    f32x4 r00 = *(const f32x4*)(xb + (h0 << 5) + wa);
    f32x4 r01 = *(const f32x4*)(xb + (h0 << 5) + wa + 4);
    f32x4 r10 = *(const f32x4*)(xb + (h1 << 5) + wa);
    f32x4 r11 = *(const f32x4*)(xb + (h1 << 5) + wa + 4);
    #pragma unroll
    for (int k = 0; k < 4; ++k) {
        usl[k][i] = r00[k]; usl[4 + k][i] = r01[k];
        usl[8 + k][i] = r10[k]; usl[12 + k][i] = r11[k];
    }
    float sv = s1[b*CC + i];
    #pragma unroll
    for (int dq = 0; dq < 4; ++dq) {
        int q = q0 + dq;
        float cwf = q * scale; int w0 = (int)cwf; float fw = cwf - w0;
        int i0 = w0 - wa, i1 = min(w0 + 1, 31) - wa;
        float v00 = usl[i0][i], v01 = usl[i1][i];
        float v10 = usl[8 + i0][i], v11 = usl[8 + i1][i];
        float va = v00*(1.f-fh) + v10*fh;
        float vb = v01*(1.f-fh) + v11*fh;
        float v  = (va*(1.f-fw) + vb*fw) * sv;
        xs1[(((b*HP) + p + 1)*HP + (q + 1))*CC + i] = (bf16)v;
    }
}

// ---------------------------------------------------------------------------
// Implicit-GEMM 3x3 conv, 8-phase counted-vmcnt schedule (T2+T3+T4+T5).
// M=32768, N=512, K=9 taps x 512. BM=BN=256, BK=64, 512 thr = 8 waves (2Mx4N),
// per-wave 128x64 via 8x4 of mfma_f32_16x16x32_bf16.
// LDS 128 KiB: A,B each 2 dbufs x 256rows x 64k bf16, rows PERMUTED so each
// 16KB half-tile == exactly the rows first-read by one phase:
//   A: LDSrow = fh*128 + wm*64 + j   (tile row = wm*128 + fh*64 + j)
//   B: LDSrow = nh*128 + wn*32 + jj  (tile row = wn*64 + nh*32 + jj)
// Slot-XOR swizzle (slot ^ row&7) on both staging source and ds_read.
// Per iteration (2 K-steps): 8 phases, each stages one half-tile (2 gload16),
// reads one fragment set, runs 16 MFMA under setprio(1). s_waitcnt vmcnt(4)
// (never 0) at ends of ph1,2,4,5,6,8 -- every half staged 4 phases before
// first read, waited >=3 phases after issue. One raw s_barrier per phase.
// ---------------------------------------------------------------------------
#define VM4 asm volatile("s_waitcnt vmcnt(4)" ::: "memory")
#define BARR do { asm volatile("" ::: "memory"); __builtin_amdgcn_s_barrier(); \
                  asm volatile("" ::: "memory"); } while (0)

#define STAGE_A(d, h, U) do { \
    gload16((U) + aThr + (h)*(HP*1024),                 ldsA + (d)*32768 + (h)*16384); \
    gload16((U) + aThr + (h)*(HP*1024) + 2*(HP*1024),   ldsA + (d)*32768 + (h)*16384 + 8192); \
} while (0)

#define STAGE_B(d, h, U) do { \
    gload16((U) + bThr + (h)*32768,                     ldsB + (d)*32768 + (h)*16384); \
    gload16((U) + bThr + (h)*32768 + 131072,            ldsB + (d)*32768 + (h)*16384 + 8192); \
} while (0)

#define LOAD_A(d, fh) do { \
    _Pragma("unroll") \
    for (int fmq = 0; fmq < 4; ++fmq) { \
        afr[fmq][0] = *(const bf16x8*)(aRd + (d)*32768 + (fh)*16384 + fmq*2048 + swz0); \
        afr[fmq][1] = *(const bf16x8*)(aRd + (d)*32768 + (fh)*16384 + fmq*2048 + swz1); \
    } } while (0)

#define LOAD_B(d, nh) do { \
    _Pragma("unroll") \
    for (int fnq = 0; fnq < 2; ++fnq) { \
        bfr[fnq][0] = *(const bf16x8*)(bRd + (d)*32768 + (nh)*16384 + fnq*2048 + swz0); \
        bfr[fnq][1] = *(const bf16x8*)(bRd + (d)*32768 + (nh)*16384 + fnq*2048 + swz1); \
    } } while (0)

#define QUAD(fh, nh) do { \
    __builtin_amdgcn_s_setprio(1); \
    _Pragma("unroll") \
    for (int kc = 0; kc < 2; ++kc) \
    { _Pragma("unroll") \
      for (int fmq = 0; fmq < 4; ++fmq) \
      { _Pragma("unroll") \
        for (int fnq = 0; fnq < 2; ++fnq) \
            acc[(fh)*4+fmq][(nh)*2+fnq] = __builtin_amdgcn_mfma_f32_16x16x32_bf16( \
                afr[fmq][kc], bfr[fnq][kc], acc[(fh)*4+fmq][(nh)*2+fnq], 0, 0, 0); } } \
    __builtin_amdgcn_s_setprio(0); } while (0)

// 4-phase group: compute dbuf dc, stage next tile into dbuf sd from Au/Bu.
#define PHGROUP(dc, sd, Au, Bu, doStage) do { \
    if (doStage) STAGE_A(sd, 0, Au); \
    LOAD_A(dc, 0); LOAD_B(dc, 0); \
    QUAD(0, 0); \
    VM4; BARR; \
    if (doStage) STAGE_B(sd, 0, Bu); \
    LOAD_A(dc, 1); \
    QUAD(1, 0); \
    VM4; BARR; \
    if (doStage) STAGE_A(sd, 1, Au); \
    LOAD_B(dc, 1); \
    QUAD(1, 1); \
    BARR; \
    if (doStage) STAGE_B(sd, 1, Bu); \
    LOAD_A(dc, 0); \
    QUAD(0, 1); \
    VM4; BARR; \
} while (0)

template<int PHASE>
__global__ __launch_bounds__(512, 2) void conv_gemm(
    const bf16* __restrict__ xs, const bf16* __restrict__ keffT,
    const float* __restrict__ dg, const float* __restrict__ noise,
    const float* __restrict__ nsw, const float* __restrict__ nsb,
    const float* __restrict__ nbw, const float* __restrict__ nbb,
    const float* __restrict__ biasv, const float* __restrict__ stnext,
    bf16* __restrict__ outb, float* __restrict__ outf) {
    __shared__ __attribute__((aligned(16))) bf16 As[32768];   // 64 KB: 2 dbuf x 256x64
    __shared__ __attribute__((aligned(16))) bf16 Bs[32768];   // 64 KB
    const int tid = threadIdx.x;
    const int wave = tid >> 6, lane = tid & 63;
    // XCD swizzle: 256 wgs, %8==0 -> bijective; each XCD: 16 mtiles x both ntiles.
    const int tileId = ((blockIdx.x & 7) << 5) + (blockIdx.x >> 3);
    const int mtile = tileId >> 1, ntile = tileId & 1;
    const int m0 = mtile << 8, n0 = ntile << 8;
    const int b  = m0 >> 12;
    const int p0 = (m0 & 4095) >> 6;
    const int wm = wave >> 2, wn = wave & 3;
    const int l15 = lane & 15;

    // staging thread constants (source pre-XOR-swizzled, dest linear)
    const int srcSwz = (((tid & 7) ^ ((tid >> 3) & 7)) << 4);
    const int aThr = ((tid >> 3) << 10) + srcSwz;
    const int bThr = (((tid >> 8) & 1) << 16) + (((tid >> 3) & 31) << 10) + srcSwz;
    char* const ldsA = (char*)As + tid*16;
    char* const ldsB = (char*)Bs + tid*16;

    // fragment read bases (row*128 + (slot ^ row&7)*16)
    const char* const aRd = (const char*)As + (((wm << 6) + l15) << 7);
    const char* const bRd = (const char*)Bs + (((wn << 5) + l15) << 7);
    const int swz0 = (((lane >> 4)    ) ^ (lane & 7)) << 4;
    const int swz1 = (((lane >> 4) | 4) ^ (lane & 7)) << 4;

    f32x4 acc[8][4];
    #pragma unroll
    for (int i_ = 0; i_ < 8; ++i_)
        #pragma unroll
        for (int j_ = 0; j_ < 4; ++j_) acc[i_][j_] = f32x4{0.f, 0.f, 0.f, 0.f};
    bf16x8 afr[4][2], bfr[2][2];

    // uniform staging bases per K-step st (0..71): tap t=st>>3, k0=(st&7)*64
    auto abase = [&](int st) -> const char* {
        int t = st >> 3; int dh = (t*11) >> 5; int dw = t - dh*3;
        return (const char*)xs + ((size_t)((b*HP + p0 + dh)*HP + dw) << 10) + ((st & 7) << 7);
    };
    auto bbase = [&](int st) -> const char* {
        int t = st >> 3;
        return (const char*)keffT + ((size_t)(t*CC + n0) << 10) + ((st & 7) << 7);
    };

    // prologue: stage K-step 0 into dbuf0 (Ah0,Bh0,Ah1,Bh1), drain first 2 halves
    {
        const char* a0 = abase(0); const char* b0 = bbase(0);
        STAGE_A(0, 0, a0); STAGE_B(0, 0, b0);
        STAGE_A(0, 1, a0); STAGE_B(0, 1, b0);
        VM4; BARR;
    }

    #pragma unroll 1
    for (int it = 0; it < 36; ++it) {
        const char* a1 = abase(2*it + 1);
        const char* b1 = bbase(2*it + 1);
        const bool more = (it < 35);
        const char* a2 = abase(2*it + 2);   // address math only when !more
        const char* b2 = bbase(2*it + 2);
        PHGROUP(0, 1, a1, b1, true);        // compute K-step 2it (dbuf0), stage 2it+1
        PHGROUP(1, 0, a2, b2, more);        // compute K-step 2it+1 (dbuf1), stage 2it+2
    }

    // epilogue: v*dg -> noise modulation -> +bias -> lrelu -> route
    const float* dgb = dg + b*CC;
    int nIdx[4]; float pdg[4], pnsw[4], pnsb[4], pnbw[4], pnbb[4], pbias[4], pst[4];
    #pragma unroll
    for (int fn = 0; fn < 4; ++fn) {
        int n = n0 + (wn << 6) + (fn << 4) + l15;
        nIdx[fn] = n;
        pdg[fn] = dgb[n]; pnsw[fn] = nsw[n]; pnsb[fn] = nsb[n];
        pnbw[fn] = nbw[n]; pnbb[fn] = nbb[n]; pbias[fn] = biasv[n];
        if (PHASE == 1) pst[fn] = stnext[b*CC + n]; else pst[fn] = 0.f;
    }
    #pragma unroll
    for (int fm = 0; fm < 8; ++fm) {
        #pragma unroll
        for (int r = 0; r < 4; ++r) {
            int mloc = m0 + (wm << 7) + (fm << 4) + ((lane >> 4) << 2) + r;
            float ns = noise[mloc];
            int prow = (mloc & 4095) >> 6, qcol = mloc & 63;
            #pragma unroll
            for (int fn = 0; fn < 4; ++fn) {
                float v = acc[fm][fn][r] * pdg[fn];
                v = v * (ns*pnsw[fn] + pnsb[fn]) + (ns*pnbw[fn] + pnbb[fn]) + pbias[fn];
                v = fmaxf(v, 0.2f*v);   // leaky relu 0.2
                if (PHASE == 1) {
                    outb[(((b*HP) + prow + 1)*HP + (qcol + 1))*CC + nIdx[fn]] =
                        (bf16)(v * pst[fn]);
                } else {
                    outf[((b*CC + nIdx[fn]) << 12) + (mloc & 4095)] = v;
                }
            }
        }
    }
}

// block = 64 consecutive pixels, 4 waves split the o-range (128 each).
__global__ void rgb_kernel(const float* __restrict__ xf, const float* __restrict__ rgbw,
                           const float* __restrict__ rgbb, float* __restrict__ out) {
    __shared__ float red[3][4][64];
    int tid = threadIdx.x;
    int wv = tid >> 6, ln = tid & 63;
    int pix = blockIdx.x * 64 + ln;
    int b = pix >> 12, rem = pix & 4095;
    const float* xb = xf + (((size_t)b*CC) << 12) + rem;
    float a0 = 0.f, a1 = 0.f, a2 = 0.f;
    int o0 = wv << 7;
    #pragma unroll 8
    for (int o = o0; o < o0 + 128; ++o) {
        float xv = xb[(size_t)o << 12];
        a0 += xv * rgbw[o]; a1 += xv * rgbw[CC+o]; a2 += xv * rgbw[2*CC+o];
    }
    red[0][wv][ln] = a0; red[1][wv][ln] = a1; red[2][wv][ln] = a2;
    __syncthreads();
    if (wv == 0) {
        const float he = 0.03f * 0.04419417382415922f;
        #pragma unroll
        for (int c = 0; c < 3; ++c) {
            float s = red[c][0][ln] + red[c][1][ln] + red[c][2][ln] + red[c][3][ln];
            out[(b*3+c)*4096 + rem] = s*he + rgbb[c];
        }
    }
}

extern "C" void kernel_launch(void* const* d_in, const int* in_sizes, int n_in,
                              void* d_out, int out_size, void* d_ws, size_t ws_size,
                              hipStream_t stream) {
    const float* x      = (const float*)d_in[0];
    const float* w      = (const float*)d_in[1];
    const float* noise1 = (const float*)d_in[2];
    const float* noise2 = (const float*)d_in[3];
    const float* conv1w = (const float*)d_in[4];
    const float* bias1  = (const float*)d_in[5];
    const float* conv2w = (const float*)d_in[6];
    const float* bias2  = (const float*)d_in[7];
    const float* A1w = (const float*)d_in[8];
    const float* A1b = (const float*)d_in[9];
    const float* A2w = (const float*)d_in[10];
    const float* A2b = (const float*)d_in[11];
    const float* B1sw = (const float*)d_in[12];
    const float* B1sb = (const float*)d_in[13];
    const float* B1bw = (const float*)d_in[14];
    const float* B1bb = (const float*)d_in[15];
    const float* B2sw = (const float*)d_in[16];
    const float* B2sb = (const float*)d_in[17];
    const float* B2bw = (const float*)d_in[18];
    const float* B2bb = (const float*)d_in[19];
    const float* rgbw = (const float*)d_in[20];
    const float* rgbb = (const float*)d_in[21];

    char* ws = (char*)d_ws;
    size_t off = 0;
    auto alloc = [&](size_t bytes) { char* p = ws + off; off += (bytes + 255) & ~(size_t)255; return p; };
    const size_t xsBytes = (size_t)BB*HP*HP*CC*2;
    bf16* xs1 = (bf16*)alloc(xsBytes);
    bf16* xs2 = (bf16*)alloc(xsBytes);
    bf16* kT1 = (bf16*)alloc((size_t)9*CC*CC*2);
    bf16* kT2 = (bf16*)alloc((size_t)9*CC*CC*2);
    float* S21 = (float*)alloc((size_t)CC*CC*4);
    float* S22 = (float*)alloc((size_t)CC*CC*4);
    float* s1  = (float*)alloc(BB*CC*4);
    float* s2  = (float*)alloc(BB*CC*4);
    float* dg1 = (float*)alloc(BB*CC*4);
    float* dg2 = (float*)alloc(BB*CC*4);

    float* outx   = (float*)d_out;
    float* outrgb = outx + (size_t)BB*CC*HO*HO;

    hipMemsetAsync(xs1, 0, xsBytes, stream);
    hipMemsetAsync(xs2, 0, xsBytes, stream);

    const float gain = 1.41421356237309515f;
    const float he = gain / sqrtf(512.f * 9.f);
    prep_weights<<<CC*CC/256, 256, 0, stream>>>(conv1w, S21, kT1, he);
    prep_weights<<<CC*CC/256, 256, 0, stream>>>(conv2w, S22, kT2, he);
    style_kernel<<<2*BB*CC/4, 256, 0, stream>>>(w, A1w, A1b, A2w, A2b, s1, s2);
    demod_kernel<<<2*BB*CC/4, 256, 0, stream>>>(s1, S21, s2, S22, dg1, dg2, gain);
    upsample_mod<<<BB*HO*16, CC, 0, stream>>>(x, s1, xs1);
    conv_gemm<1><<<(NPIX/256)*(CC/256), 512, 0, stream>>>(
        xs1, kT1, dg1, noise1, B1sw, B1sb, B1bw, B1bb, bias1, s2, xs2, nullptr);
    conv_gemm<2><<<(NPIX/256)*(CC/256), 512, 0, stream>>>(
        xs2, kT2, dg2, noise2, B2sw, B2sb, B2bw, B2bb, bias2, nullptr, nullptr, outx);
    rgb_kernel<<<NPIX/64, 256, 0, stream>>>(outx, rgbw, rgbb, outrgb);
}

// Round 3
// 384.335 us; speedup vs baseline: 2.0372x; 1.0225x over previous
//
#include <hip/hip_runtime.h>
#include <hip/hip_bf16.h>

#define BB 8
#define CC 512
#define HO 64
#define HP 66
#define NPIX (BB*HO*HO)   // 32768

typedef float f32x4 __attribute__((ext_vector_type(4)));
typedef __bf16 bf16x8 __attribute__((ext_vector_type(8)));
using bf16 = __hip_bfloat16;

__device__ __forceinline__ void gload16(const void* g, void* l) {
    __builtin_amdgcn_global_load_lds((const __attribute__((address_space(1))) void*)g,
                                     (__attribute__((address_space(3))) void*)l, 16, 0, 0);
}

__device__ __forceinline__ float waveRedSum(float v) {
    #pragma unroll
    for (int off = 32; off; off >>= 1) v += __shfl_down(v, off);
    return v;
}

// thread t -> (i = t&511, o = t>>9). Reads W[i][o][0..8] (contiguous 36B),
// writes S2ho[o][i] = he^2 * sum W^2, and keffT[tap][o][i] = he*W[i][o][8-tap].
__global__ void prep_weights(const float* __restrict__ Wsrc, float* __restrict__ S2ho,
                             bf16* __restrict__ keffT, float he) {
    int t = blockIdx.x * blockDim.x + threadIdx.x;
    int i = t & (CC-1), o = t >> 9;
    const float* wp = Wsrc + (i*CC + o)*9;
    float v[9]; float s2 = 0.f;
    #pragma unroll
    for (int k = 0; k < 9; ++k) { v[k] = wp[k] * he; s2 += v[k]*v[k]; }
    S2ho[o*CC + i] = s2;
    #pragma unroll
    for (int tp = 0; tp < 9; ++tp) keffT[(tp*CC + o)*CC + i] = (bf16)v[8 - tp];
}

// one wave per (set, b, i): style[b,i] = sum_d w[b,d]*A[i,d]/sqrt(512) + Ab[i]
__global__ void style_kernel(const float* __restrict__ w,
                             const float* __restrict__ A1, const float* __restrict__ A1b,
                             const float* __restrict__ A2, const float* __restrict__ A2b,
                             float* __restrict__ s1, float* __restrict__ s2) {
    int wid = (blockIdx.x * blockDim.x + threadIdx.x) >> 6;
    int lane = threadIdx.x & 63;
    int set = wid >= BB*CC; int rem = set ? wid - BB*CC : wid;
    int b = rem >> 9, i = rem & (CC-1);
    const float* A = set ? A2 : A1;
    const float* wb = w + b*CC;
    float sum = 0.f;
    for (int d = lane; d < CC; d += 64) sum += wb[d] * A[i*CC + d];
    sum = waveRedSum(sum);
    if (lane == 0) {
        float r = sum * 0.04419417382415922f + (set ? A2b : A1b)[i];
        (set ? s2 : s1)[b*CC + i] = r;
    }
}

// one wave per (set, b, o): dg = gain * rsqrt(sum_i style^2 * S2ho[o][i] + eps)
__global__ void demod_kernel(const float* __restrict__ s1, const float* __restrict__ S21,
                             const float* __restrict__ s2, const float* __restrict__ S22,
                             float* __restrict__ dg1, float* __restrict__ dg2, float gain) {
    int wid = (blockIdx.x * blockDim.x + threadIdx.x) >> 6;
    int lane = threadIdx.x & 63;
    int set = wid >= BB*CC; int rem = set ? wid - BB*CC : wid;
    int b = rem >> 9, o = rem & (CC-1);
    const float* st = (set ? s2 : s1) + b*CC;
    const float* S2 = (set ? S22 : S21) + o*CC;
    float sum = 0.f;
    for (int i = lane; i < CC; i += 64) { float sv = st[i]; sum += sv*sv*S2[i]; }
    sum = waveRedSum(sum);
    if (lane == 0) (set ? dg2 : dg1)[b*CC + o] = gain * rsqrtf(sum + 1e-8f);
}

// block = (b, p, q-group of 4), 512 threads = channels.
__global__ void upsample_mod(const float* __restrict__ x, const float* __restrict__ s1,
                             bf16* __restrict__ xs1) {
    __shared__ float usl[16][CC];
    int blk = blockIdx.x;
    int i = threadIdx.x;
    int b = blk >> 10, rem = blk & 1023, p = rem >> 4, q0 = (rem & 15) << 2;
    const float scale = 31.0f / 63.0f;
    float chf = p * scale; int h0 = (int)chf; float fh = chf - h0; int h1 = min(h0 + 1, 31);
    int wa = min(((int)(q0 * scale)) & ~3, 24);    // 4-aligned, wa+7 <= 31
    const float* xb = x + ((size_t)(b*CC + i) << 10);
    f32x4 r00 = *(const f32x4*)(xb + (h0 << 5) + wa);
    f32x4 r01 = *(const f32x4*)(xb + (h0 << 5) + wa + 4);
    f32x4 r10 = *(const f32x4*)(xb + (h1 << 5) + wa);
    f32x4 r11 = *(const f32x4*)(xb + (h1 << 5) + wa + 4);
    #pragma unroll
    for (int k = 0; k < 4; ++k) {
        usl[k][i] = r00[k]; usl[4 + k][i] = r01[k];
        usl[8 + k][i] = r10[k]; usl[12 + k][i] = r11[k];
    }
    float sv = s1[b*CC + i];
    #pragma unroll
    for (int dq = 0; dq < 4; ++dq) {
        int q = q0 + dq;
        float cwf = q * scale; int w0 = (int)cwf; float fw = cwf - w0;
        int i0 = w0 - wa, i1 = min(w0 + 1, 31) - wa;
        float v00 = usl[i0][i], v01 = usl[i1][i];
        float v10 = usl[8 + i0][i], v11 = usl[8 + i1][i];
        float va = v00*(1.f-fh) + v10*fh;
        float vb = v01*(1.f-fh) + v11*fh;
        float v  = (va*(1.f-fw) + vb*fw) * sv;
        xs1[(((b*HP) + p + 1)*HP + (q + 1))*CC + i] = (bf16)v;
    }
}

// ---------------------------------------------------------------------------
// Implicit-GEMM 3x3 conv, m201-faithful 8-phase schedule (T2+T3+T4+T5).
// BM=BN=256, BK=64, 512 thr = 8 waves (2Mx4N), per-wave 128x64.
// Per phase: {ds_read subtile || stage 1 half-tile} -> s_barrier -> lgkmcnt(0)
// -> 16 MFMA (setprio 1) -> [counted vmcnt] -> s_barrier.  Reads are issued one
// barrier AHEAD of their MFMA, so LDS latency hides under other waves' MFMA.
// Quadrants (fh,nh): ph0 (0,0) reads A-h0+B-h0 (12 b128); ph1 (0,1) reads B-h1
// (4); ph2 (1,1) reads A-h1 (8); ph3 (1,0) reads nothing (B kept in regs).
// Staging stream, depth 5 phases (unit U = 4s+u staged at phase U-5):
//   ph0: B(s+1,h0), ph1: B(s+1,h1), ph2: A(s+1,h1), ph3: A(s+2,h0).
// Ledger: vmcnt(4) at ph0 end -> u2,u3 of s landed; vmcnt(6) at ph3 end ->
// u0,u1 of s+1 landed. Tail (no ph3 stage): vmcnt(0) drains the stream.
// ---------------------------------------------------------------------------
#define SB  __builtin_amdgcn_sched_barrier(0)
#define BAR __builtin_amdgcn_s_barrier()
#define VMC(n)  asm volatile("s_waitcnt vmcnt(" #n ")" ::: "memory")
#define LGKM(n) asm volatile("s_waitcnt lgkmcnt(" #n ")" ::: "memory")

#define STAGE_A(d, h, U) do { \
    gload16((U) + aThr + (h)*(HP*1024),                 ldsA + (d)*32768 + (h)*16384); \
    gload16((U) + aThr + (h)*(HP*1024) + 2*(HP*1024),   ldsA + (d)*32768 + (h)*16384 + 8192); \
} while (0)

#define STAGE_B(d, h, U) do { \
    gload16((U) + bThr + (h)*32768,                     ldsB + (d)*32768 + (h)*16384); \
    gload16((U) + bThr + (h)*32768 + 131072,            ldsB + (d)*32768 + (h)*16384 + 8192); \
} while (0)

#define LOAD_A(d, fh) do { \
    _Pragma("unroll") \
    for (int fmq = 0; fmq < 4; ++fmq) { \
        afr[fmq][0] = *(const bf16x8*)(aRd + (d)*32768 + (fh)*16384 + fmq*2048 + swz0); \
        afr[fmq][1] = *(const bf16x8*)(aRd + (d)*32768 + (fh)*16384 + fmq*2048 + swz1); \
    } } while (0)

#define LOAD_B(d, nh) do { \
    _Pragma("unroll") \
    for (int fnq = 0; fnq < 2; ++fnq) { \
        bfr[nh][fnq][0] = *(const bf16x8*)(bRd + (d)*32768 + (nh)*16384 + fnq*2048 + swz0); \
        bfr[nh][fnq][1] = *(const bf16x8*)(bRd + (d)*32768 + (nh)*16384 + fnq*2048 + swz1); \
    } } while (0)

#define QUAD(fh, nh) do { \
    __builtin_amdgcn_s_setprio(1); \
    _Pragma("unroll") \
    for (int kc = 0; kc < 2; ++kc) \
    { _Pragma("unroll") \
      for (int fmq = 0; fmq < 4; ++fmq) \
      { _Pragma("unroll") \
        for (int fnq = 0; fnq < 2; ++fnq) \
            acc[(fh)*4+fmq][(nh)*2+fnq] = __builtin_amdgcn_mfma_f32_16x16x32_bf16( \
                afr[fmq][kc], bfr[nh][fnq][kc], acc[(fh)*4+fmq][(nh)*2+fnq], 0, 0, 0); } } \
    __builtin_amdgcn_s_setprio(0); } while (0)

// one K-step = 4 phases. cur/nxt are dbuf indices (compile-time).
// aN1/bN1: staging bases for step s+1; aN2: for step s+2 (into dbuf cur).
#define PHSTEP(cur, nxt, aN1, bN1, aN2, g1, g3) do { \
    /* phase 0: Q(0,0) */ \
    LOAD_A(cur, 0); \
    LOAD_B(cur, 0); \
    if (g1) STAGE_B(nxt, 0, bN1); \
    LGKM(8); SB; BAR; LGKM(0); SB; \
    QUAD(0, 0); \
    VMC(4); SB; BAR; SB; \
    /* phase 1: Q(0,1) */ \
    LOAD_B(cur, 1); \
    if (g1) STAGE_B(nxt, 1, bN1); \
    SB; BAR; LGKM(0); SB; \
    QUAD(0, 1); \
    SB; BAR; SB; \
    /* phase 2: Q(1,1) */ \
    LOAD_A(cur, 1); \
    if (g1) STAGE_A(nxt, 1, aN1); \
    SB; BAR; LGKM(0); SB; \
    QUAD(1, 1); \
    SB; BAR; SB; \
    /* phase 3: Q(1,0) */ \
    if (g3) STAGE_A(cur, 0, aN2); \
    SB; BAR; SB; \
    QUAD(1, 0); \
    if (g3) { VMC(6); } else { VMC(0); } \
    SB; BAR; SB; \
} while (0)

template<int PHASE>
__global__ __launch_bounds__(512, 2) void conv_gemm(
    const bf16* __restrict__ xs, const bf16* __restrict__ keffT,
    const float* __restrict__ dg, const float* __restrict__ noise,
    const float* __restrict__ nsw, const float* __restrict__ nsb,
    const float* __restrict__ nbw, const float* __restrict__ nbb,
    const float* __restrict__ biasv, const float* __restrict__ stnext,
    bf16* __restrict__ outb, float* __restrict__ outf) {
    __shared__ __attribute__((aligned(16))) bf16 As[32768];   // 64 KB: 2 dbuf x 256x64
    __shared__ __attribute__((aligned(16))) bf16 Bs[32768];   // 64 KB
    const int tid = threadIdx.x;
    const int wave = tid >> 6, lane = tid & 63;
    // XCD swizzle: 256 wgs, %8==0 -> bijective.
    const int tileId = ((blockIdx.x & 7) << 5) + (blockIdx.x >> 3);
    const int mtile = tileId >> 1, ntile = tileId & 1;
    const int m0 = mtile << 8, n0 = ntile << 8;
    const int b  = m0 >> 12;
    const int p0 = (m0 & 4095) >> 6;
    const int wm = wave >> 2, wn = wave & 3;
    const int l15 = lane & 15;

    // staging thread constants (source pre-XOR-swizzled, dest linear)
    const int srcSwz = (((tid & 7) ^ ((tid >> 3) & 7)) << 4);
    const int aThr = ((tid >> 3) << 10) + srcSwz;
    const int bThr = (((tid >> 8) & 1) << 16) + (((tid >> 3) & 31) << 10) + srcSwz;
    char* const ldsA = (char*)As + tid*16;
    char* const ldsB = (char*)Bs + tid*16;

    // fragment read bases (row*128 + (slot ^ row&7)*16)
    const char* const aRd = (const char*)As + (((wm << 6) + l15) << 7);
    const char* const bRd = (const char*)Bs + (((wn << 5) + l15) << 7);
    const int swz0 = (((lane >> 4)    ) ^ (lane & 7)) << 4;
    const int swz1 = (((lane >> 4) | 4) ^ (lane & 7)) << 4;

    f32x4 acc[8][4];
    #pragma unroll
    for (int i_ = 0; i_ < 8; ++i_)
        #pragma unroll
        for (int j_ = 0; j_ < 4; ++j_) acc[i_][j_] = f32x4{0.f, 0.f, 0.f, 0.f};
    bf16x8 afr[4][2], bfr[2][2][2];

    // uniform staging bases per K-step st (0..71): tap t=st>>3, k0=(st&7)*64
    auto abase = [&](int st) -> const char* {
        int t = st >> 3; int dh = (t*11) >> 5; int dw = t - dh*3;
        return (const char*)xs + ((size_t)((b*HP + p0 + dh)*HP + dw) << 10) + ((st & 7) << 7);
    };
    auto bbase = [&](int st) -> const char* {
        int t = st >> 3;
        return (const char*)keffT + ((size_t)(t*CC + n0) << 10) + ((st & 7) << 7);
    };

    // prologue: stage units 0..4 in read order, leave units 2..4 in flight
    {
        const char* a0 = abase(0); const char* b0 = bbase(0); const char* a1 = abase(1);
        STAGE_A(0, 0, a0);
        STAGE_B(0, 0, b0);
        STAGE_B(0, 1, b0);
        STAGE_A(0, 1, a0);
        STAGE_A(1, 0, a1);
        VMC(6); SB; BAR; SB;
    }

    #pragma unroll 1
    for (int it = 0; it < 36; ++it) {
        const bool more = (it < 35);
        const char* aE = abase(2*it + 1); const char* bE = bbase(2*it + 1);
        const char* aO = abase(2*it + 2); const char* bO = bbase(2*it + 2);
        const char* aO2 = abase(2*it + 3);
        PHSTEP(0, 1, aE, bE, aO,  true, more);   // compute K-step 2it   (dbuf0)
        PHSTEP(1, 0, aO, bO, aO2, more, more);   // compute K-step 2it+1 (dbuf1)
    }

    // epilogue: v*dg -> noise modulation -> +bias -> lrelu -> route
    const float* dgb = dg + b*CC;
    int nIdx[4]; float pdg[4], pnsw[4], pnsb[4], pnbw[4], pnbb[4], pbias[4], pst[4];
    #pragma unroll
    for (int fn = 0; fn < 4; ++fn) {
        int n = n0 + (wn << 6) + (fn << 4) + l15;
        nIdx[fn] = n;
        pdg[fn] = dgb[n]; pnsw[fn] = nsw[n]; pnsb[fn] = nsb[n];
        pnbw[fn] = nbw[n]; pnbb[fn] = nbb[n]; pbias[fn] = biasv[n];
        if (PHASE == 1) pst[fn] = stnext[b*CC + n]; else pst[fn] = 0.f;
    }
    #pragma unroll
    for (int fm = 0; fm < 8; ++fm) {
        #pragma unroll
        for (int r = 0; r < 4; ++r) {
            int mloc = m0 + (wm << 7) + (fm << 4) + ((lane >> 4) << 2) + r;
            float ns = noise[mloc];
            int prow = (mloc & 4095) >> 6, qcol = mloc & 63;
            #pragma unroll
            for (int fn = 0; fn < 4; ++fn) {
                float v = acc[fm][fn][r] * pdg[fn];
                v = v * (ns*pnsw[fn] + pnsb[fn]) + (ns*pnbw[fn] + pnbb[fn]) + pbias[fn];
                v = fmaxf(v, 0.2f*v);   // leaky relu 0.2
                if (PHASE == 1) {
                    outb[(((b*HP) + prow + 1)*HP + (qcol + 1))*CC + nIdx[fn]] =
                        (bf16)(v * pst[fn]);
                } else {
                    outf[((b*CC + nIdx[fn]) << 12) + (mloc & 4095)] = v;
                }
            }
        }
    }
}

// block = 64 consecutive pixels, 4 waves split the o-range (128 each).
__global__ void rgb_kernel(const float* __restrict__ xf, const float* __restrict__ rgbw,
                           const float* __restrict__ rgbb, float* __restrict__ out) {
    __shared__ float red[3][4][64];
    int tid = threadIdx.x;
    int wv = tid >> 6, ln = tid & 63;
    int pix = blockIdx.x * 64 + ln;
    int b = pix >> 12, rem = pix & 4095;
    const float* xb = xf + (((size_t)b*CC) << 12) + rem;
    float a0 = 0.f, a1 = 0.f, a2 = 0.f;
    int o0 = wv << 7;
    #pragma unroll 8
    for (int o = o0; o < o0 + 128; ++o) {
        float xv = xb[(size_t)o << 12];
        a0 += xv * rgbw[o]; a1 += xv * rgbw[CC+o]; a2 += xv * rgbw[2*CC+o];
    }
    red[0][wv][ln] = a0; red[1][wv][ln] = a1; red[2][wv][ln] = a2;
    __syncthreads();
    if (wv == 0) {
        const float he = 0.03f * 0.04419417382415922f;
        #pragma unroll
        for (int c = 0; c < 3; ++c) {
            float s = red[c][0][ln] + red[c][1][ln] + red[c][2][ln] + red[c][3][ln];
            out[(b*3+c)*4096 + rem] = s*he + rgbb[c];
        }
    }
}

extern "C" void kernel_launch(void* const* d_in, const int* in_sizes, int n_in,
                              void* d_out, int out_size, void* d_ws, size_t ws_size,
                              hipStream_t stream) {
    const float* x      = (const float*)d_in[0];
    const float* w      = (const float*)d_in[1];
    const float* noise1 = (const float*)d_in[2];
    const float* noise2 = (const float*)d_in[3];
    const float* conv1w = (const float*)d_in[4];
    const float* bias1  = (const float*)d_in[5];
    const float* conv2w = (const float*)d_in[6];
    const float* bias2  = (const float*)d_in[7];
    const float* A1w = (const float*)d_in[8];
    const float* A1b = (const float*)d_in[9];
    const float* A2w = (const float*)d_in[10];
    const float* A2b = (const float*)d_in[11];
    const float* B1sw = (const float*)d_in[12];
    const float* B1sb = (const float*)d_in[13];
    const float* B1bw = (const float*)d_in[14];
    const float* B1bb = (const float*)d_in[15];
    const float* B2sw = (const float*)d_in[16];
    const float* B2sb = (const float*)d_in[17];
    const float* B2bw = (const float*)d_in[18];
    const float* B2bb = (const float*)d_in[19];
    const float* rgbw = (const float*)d_in[20];
    const float* rgbb = (const float*)d_in[21];

    char* ws = (char*)d_ws;
    size_t off = 0;
    auto alloc = [&](size_t bytes) { char* p = ws + off; off += (bytes + 255) & ~(size_t)255; return p; };
    const size_t xsBytes = (size_t)BB*HP*HP*CC*2;
    bf16* xs1 = (bf16*)alloc(xsBytes);
    bf16* xs2 = (bf16*)alloc(xsBytes);
    bf16* kT1 = (bf16*)alloc((size_t)9*CC*CC*2);
    bf16* kT2 = (bf16*)alloc((size_t)9*CC*CC*2);
    float* S21 = (float*)alloc((size_t)CC*CC*4);
    float* S22 = (float*)alloc((size_t)CC*CC*4);
    float* s1  = (float*)alloc(BB*CC*4);
    float* s2  = (float*)alloc(BB*CC*4);
    float* dg1 = (float*)alloc(BB*CC*4);
    float* dg2 = (float*)alloc(BB*CC*4);

    float* outx   = (float*)d_out;
    float* outrgb = outx + (size_t)BB*CC*HO*HO;

    hipMemsetAsync(xs1, 0, xsBytes, stream);
    hipMemsetAsync(xs2, 0, xsBytes, stream);

    const float gain = 1.41421356237309515f;
    const float he = gain / sqrtf(512.f * 9.f);
    prep_weights<<<CC*CC/256, 256, 0, stream>>>(conv1w, S21, kT1, he);
    prep_weights<<<CC*CC/256, 256, 0, stream>>>(conv2w, S22, kT2, he);
    style_kernel<<<2*BB*CC/4, 256, 0, stream>>>(w, A1w, A1b, A2w, A2b, s1, s2);
    demod_kernel<<<2*BB*CC/4, 256, 0, stream>>>(s1, S21, s2, S22, dg1, dg2, gain);
    upsample_mod<<<BB*HO*16, CC, 0, stream>>>(x, s1, xs1);
    conv_gemm<1><<<(NPIX/256)*(CC/256), 512, 0, stream>>>(
        xs1, kT1, dg1, noise1, B1sw, B1sb, B1bw, B1bb, bias1, s2, xs2, nullptr);
    conv_gemm<2><<<(NPIX/256)*(CC/256), 512, 0, stream>>>(
        xs2, kT2, dg2, noise2, B2sw, B2sb, B2bw, B2bb, bias2, nullptr, nullptr, outx);
    rgb_kernel<<<NPIX/64, 256, 0, stream>>>(outx, rgbw, rgbb, outrgb);
}